// Round 3
// baseline (192.219 us; speedup 1.0000x reference)
//
#include <hip/hip_runtime.h>
#include <math.h>

// Problem constants
#define BN 16
#define BC 256
#define BK 8
#define BM 63
#define MO 56
#define PLANE (BM * BM)                 // 3969
#define XS_STRIDE 68                    // 16B-multiple stride; bank-group pattern (lx-ly+r+c)%8 is perfectly even
#define XS_SIZE (BM * XS_STRIDE + 8)    // +8 pad so idle-lane b128 reads stay in-bounds

// Parallelization: 2-wave blocks (128 thr), per-lane tile 7 rows x 4 cols.
// Lane grid 8(ly) x 8(lx) per wave; the 2 waves split columns: colblk = lx + 8*wv
// covers 16 x 4 = 64 cols; colblk 14,15 idle (56 needed). T_CH=4 channels/block.
#define T_CH 4
#define NCHUNK (BC / T_CH)              // 64 -> grid 16x64 = 1024 blocks (4/CU, 8 waves/CU)
#define NTHREADS 128

__global__ __launch_bounds__(NTHREADS, 2)
void bhat_kernel(const float* __restrict__ z,
                 const float* __restrict__ x,
                 const float* __restrict__ w,
                 float* __restrict__ out)
{
    __shared__ __align__(16) float xs[XS_SIZE];   // 17.2 KB

    const int n      = blockIdx.x;
    const int c0     = blockIdx.y * T_CH;
    const int tid    = threadIdx.x;
    const int lane   = tid & 63;
    const int wv     = tid >> 6;
    const int ly     = lane >> 3;
    const int lx     = lane & 7;
    const int colblk = lx + 8 * wv;     // 0..15
    const int col0   = colblk * 4;      // 0..60, 16B-aligned in xs
    const int row0   = ly * 7;          // 0..49
    const bool active = (colblk < 14);  // colblk 14,15 compute garbage, never store

    float acc[7][4];
#pragma unroll
    for (int a = 0; a < 7; ++a)
#pragma unroll
        for (int b = 0; b < 4; ++b) acc[a][b] = 0.0f;

    for (int ci = 0; ci < T_CH; ++ci) {
        const int c = c0 + ci;
        const float* __restrict__ xp = x + (size_t)(n * BC + c) * PLANE;

        __syncthreads();   // previous round's xs readers done
        // Stage sqrt(x) once per element. 3969 elems / 128 thr = 31.01 -> 32 iters.
        for (int j = 0; j < 32; ++j) {
            int i = tid + NTHREADS * j;
            if (i < PLANE) {
                unsigned r  = (unsigned)i / 63u;
                unsigned cc = (unsigned)i - r * 63u;
                xs[r * XS_STRIDE + cc] = sqrtf(xp[i]);
            }
        }
        __syncthreads();

        const float wsc = w[c] * (1.0f / 64.0f);        // fold 1/k^2 and weight into z
        const float* __restrict__ zp = z + (size_t)(n * BC + c) * 64;

#pragma unroll
        for (int p2 = 0; p2 < 4; ++p2) {
            const int p = 2 * p2;
            // z rows p, p+1 = 16 consecutive floats, 16B-aligned
            float4 za = *(const float4*)(zp + p * 8);
            float4 zb = *(const float4*)(zp + p * 8 + 4);
            float4 zc = *(const float4*)(zp + p * 8 + 8);
            float4 zd = *(const float4*)(zp + p * 8 + 12);
            float zr[2][8];
            zr[0][0] = sqrtf(za.x) * wsc;  zr[0][1] = sqrtf(za.y) * wsc;
            zr[0][2] = sqrtf(za.z) * wsc;  zr[0][3] = sqrtf(za.w) * wsc;
            zr[0][4] = sqrtf(zb.x) * wsc;  zr[0][5] = sqrtf(zb.y) * wsc;
            zr[0][6] = sqrtf(zb.z) * wsc;  zr[0][7] = sqrtf(zb.w) * wsc;
            zr[1][0] = sqrtf(zc.x) * wsc;  zr[1][1] = sqrtf(zc.y) * wsc;
            zr[1][2] = sqrtf(zc.z) * wsc;  zr[1][3] = sqrtf(zc.w) * wsc;
            zr[1][4] = sqrtf(zd.x) * wsc;  zr[1][5] = sqrtf(zd.y) * wsc;
            zr[1][6] = sqrtf(zd.z) * wsc;  zr[1][7] = sqrtf(zd.w) * wsc;

#pragma unroll
            for (int rr = 0; rr < 8; ++rr) {
                // window row r = p + rr; read 12 floats [col0, col0+12) as 3 aligned b128
                const float* xrowp = &xs[(row0 + p + rr) * XS_STRIDE + col0];
                float4 x0 = *(const float4*)(xrowp);
                float4 x1 = *(const float4*)(xrowp + 4);
                float4 x2 = *(const float4*)(xrowp + 8);
                float xr[12] = { x0.x, x0.y, x0.z, x0.w,
                                 x1.x, x1.y, x1.z, x1.w,
                                 x2.x, x2.y, x2.z, x2.w };
#pragma unroll
                for (int pp = 0; pp < 2; ++pp) {
                    if (rr == 0 && pp == 1) continue;   // a would be -1
                    if (rr == 7 && pp == 0) continue;   // a would be 7
                    const int a = rr - pp;              // output row offset, 0..6
#pragma unroll
                    for (int q = 0; q < 8; ++q) {
                        const float zv = zr[pp][q];
#pragma unroll
                        for (int b = 0; b < 4; ++b)
                            acc[a][b] = fmaf(xr[q + b], zv, acc[a][b]);
                    }
                }
            }
        }
    }

    if (active) {
        float* __restrict__ op = out + (size_t)n * (MO * MO);
#pragma unroll
        for (int a = 0; a < 7; ++a)
#pragma unroll
            for (int b = 0; b < 4; ++b)
                atomicAdd(op + (row0 + a) * MO + col0 + b, acc[a][b]);
    }
}

extern "C" void kernel_launch(void* const* d_in, const int* in_sizes, int n_in,
                              void* d_out, int out_size, void* d_ws, size_t ws_size,
                              hipStream_t stream) {
    const float* z = (const float*)d_in[0];   // (16,256,8,8)
    const float* x = (const float*)d_in[1];   // (16,256,63,63)
    const float* w = (const float*)d_in[2];   // (256)
    float* out = (float*)d_out;               // (16,1,56,56)

    (void)hipMemsetAsync(out, 0, (size_t)out_size * sizeof(float), stream);

    dim3 grid(BN, NCHUNK);
    bhat_kernel<<<grid, NTHREADS, 0, stream>>>(z, x, w, out);
}